// Round 1
// baseline (267.028 us; speedup 1.0000x reference)
//
#include <hip/hip_runtime.h>
#include <hip/hip_bf16.h>

// Gram matrix: G = X @ X^T, X = [512, 65536] fp32, out = [512, 512] fp32.
// Strategy: bf16 MFMA (16x16x32), fused fp32->bf16 conversion, 128x128 tiles,
// split-K=32 with fp32 atomicAdd accumulation into zeroed d_out.

typedef short bf16x8 __attribute__((ext_vector_type(8)));   // 8 bf16 = 4 VGPRs
typedef float f32x4  __attribute__((ext_vector_type(4)));   // MFMA acc

#define HW       65536
#define CDIM     512
#define KC       2048     // K per block (split-K = 65536/2048 = 32)
#define BK       32       // K per LDS stage = MFMA K
#define LDSS     40       // LDS row stride in bf16 (32 + 8 pad: breaks m-parity conflicts)

__device__ __forceinline__ short f2bf(float f) {
    __hip_bfloat16 h = __float2bfloat16(f);   // RNE
    short s;
    __builtin_memcpy(&s, &h, sizeof(short));
    return s;
}

__global__ __launch_bounds__(256, 2)
void gram_kernel(const float* __restrict__ X, float* __restrict__ out) {
    const int tile  = blockIdx.x;       // 0..15  -> (ti, tj) output 128x128 tile
    const int ti    = tile >> 2;
    const int tj    = tile & 3;
    const int chunk = blockIdx.y;       // 0..31  -> K chunk

    __shared__ short As[128 * LDSS];    // 10240 B
    __shared__ short Bs[128 * LDSS];

    const int t    = threadIdx.x;
    const int wave = t >> 6;
    const int lane = t & 63;
    const int wm   = wave & 1;          // 2x2 wave grid, each wave = 64x64
    const int wn   = wave >> 1;

    // --- staging mapping: 2 threads per row, 16 consecutive fp32 each ---
    const int srow  = t >> 1;           // 0..127
    const int shalf = (t & 1) * 16;     // k offset 0 or 16
    const float* pa = X + (size_t)(ti * 128 + srow) * HW + chunk * KC + shalf;
    const float* pb = X + (size_t)(tj * 128 + srow) * HW + chunk * KC + shalf;
    short* wa = As + srow * LDSS + shalf;
    short* wb = Bs + srow * LDSS + shalf;

    // --- fragment read offsets (A-operand: m = lane&15, k-group = lane>>4) ---
    const int fm = lane & 15;
    const int kg = lane >> 4;           // 0..3, each group = 8 contiguous k
    int a_off[4], b_off[4];
#pragma unroll
    for (int i = 0; i < 4; ++i) {
        a_off[i] = (wm * 64 + i * 16 + fm) * LDSS + kg * 8;
        b_off[i] = (wn * 64 + i * 16 + fm) * LDSS + kg * 8;
    }

    f32x4 acc[4][4];
#pragma unroll
    for (int i = 0; i < 4; ++i)
#pragma unroll
        for (int j = 0; j < 4; ++j)
            acc[i][j] = (f32x4){0.f, 0.f, 0.f, 0.f};

    for (int it = 0; it < KC / BK; ++it) {
        // global fp32 loads (16 floats each for A and B panel rows)
        float4 a0 = *(const float4*)(pa + 0);
        float4 a1 = *(const float4*)(pa + 4);
        float4 a2 = *(const float4*)(pa + 8);
        float4 a3 = *(const float4*)(pa + 12);
        float4 b0 = *(const float4*)(pb + 0);
        float4 b1 = *(const float4*)(pb + 4);
        float4 b2 = *(const float4*)(pb + 8);
        float4 b3 = *(const float4*)(pb + 12);

        // convert to bf16 (before barrier: independent of LDS)
        bf16x8 va0, va1, vb0, vb1;
        va0[0] = f2bf(a0.x); va0[1] = f2bf(a0.y); va0[2] = f2bf(a0.z); va0[3] = f2bf(a0.w);
        va0[4] = f2bf(a1.x); va0[5] = f2bf(a1.y); va0[6] = f2bf(a1.z); va0[7] = f2bf(a1.w);
        va1[0] = f2bf(a2.x); va1[1] = f2bf(a2.y); va1[2] = f2bf(a2.z); va1[3] = f2bf(a2.w);
        va1[4] = f2bf(a3.x); va1[5] = f2bf(a3.y); va1[6] = f2bf(a3.z); va1[7] = f2bf(a3.w);
        vb0[0] = f2bf(b0.x); vb0[1] = f2bf(b0.y); vb0[2] = f2bf(b0.z); vb0[3] = f2bf(b0.w);
        vb0[4] = f2bf(b1.x); vb0[5] = f2bf(b1.y); vb0[6] = f2bf(b1.z); vb0[7] = f2bf(b1.w);
        vb1[0] = f2bf(b2.x); vb1[1] = f2bf(b2.y); vb1[2] = f2bf(b2.z); vb1[3] = f2bf(b2.w);
        vb1[4] = f2bf(b3.x); vb1[5] = f2bf(b3.y); vb1[6] = f2bf(b3.z); vb1[7] = f2bf(b3.w);

        __syncthreads();   // prior iteration's LDS reads complete
        *(bf16x8*)(wa + 0) = va0;
        *(bf16x8*)(wa + 8) = va1;
        *(bf16x8*)(wb + 0) = vb0;
        *(bf16x8*)(wb + 8) = vb1;
        __syncthreads();   // stage visible to all waves

        bf16x8 af[4], bfr[4];
#pragma unroll
        for (int i = 0; i < 4; ++i) af[i]  = *(const bf16x8*)(As + a_off[i]);
#pragma unroll
        for (int j = 0; j < 4; ++j) bfr[j] = *(const bf16x8*)(Bs + b_off[j]);

#pragma unroll
        for (int i = 0; i < 4; ++i)
#pragma unroll
            for (int j = 0; j < 4; ++j)
                acc[i][j] = __builtin_amdgcn_mfma_f32_16x16x32_bf16(
                    af[i], bfr[j], acc[i][j], 0, 0, 0);

        pa += BK;
        pb += BK;
    }

    // --- epilogue: atomic accumulate partials ---
    // C/D layout (verified m89/m91): col = lane&15, row = (lane>>4)*4 + reg
    const int orow0 = ti * 128 + wm * 64 + (lane >> 4) * 4;
    const int ocol0 = tj * 128 + wn * 64 + (lane & 15);
#pragma unroll
    for (int i = 0; i < 4; ++i)
#pragma unroll
        for (int j = 0; j < 4; ++j)
#pragma unroll
            for (int r = 0; r < 4; ++r) {
                const int row = orow0 + i * 16 + r;
                const int col = ocol0 + j * 16;
                atomicAdd(out + row * CDIM + col, acc[i][j][r]);
            }
}

extern "C" void kernel_launch(void* const* d_in, const int* in_sizes, int n_in,
                              void* d_out, int out_size, void* d_ws, size_t ws_size,
                              hipStream_t stream) {
    const float* x = (const float*)d_in[0];
    float* out = (float*)d_out;

    // zero the accumulator (harness poisons d_out with 0xAA before every launch)
    hipMemsetAsync(d_out, 0, (size_t)out_size * sizeof(float), stream);

    dim3 grid(16, 32);   // 16 output tiles x 32 K-chunks = 512 blocks
    dim3 block(256);
    gram_kernel<<<grid, block, 0, stream>>>(x, out);
}